// Round 7
// baseline (4160.903 us; speedup 1.0000x reference)
//
#include <hip/hip_runtime.h>

#define BATCH 65536
#define DIN   256
#define DHID  512
#define BM    32
#define APAD  264   // 256+8 shorts -> 132-word row stride; stride mod 32 = 4 -> 2-way (free)
#define HPADW 520   // 512+8 shorts -> 260-word row stride; mod 32 = 4 -> 2-way (free)
#define NSTEPS 4

typedef __attribute__((ext_vector_type(8))) short short8;
typedef __attribute__((ext_vector_type(4))) float f32x4;

__device__ __forceinline__ unsigned short f2bf(float f){
  union { float f; unsigned u; } v; v.f = f;
  unsigned u = v.u;
  unsigned r = (u + 0x7FFFu + ((u >> 16) & 1u)) >> 16;   // RN-even
  return (unsigned short)r;
}
__device__ __forceinline__ float bf2f(unsigned short h){
  union { float f; unsigned u; } v; v.u = ((unsigned)h) << 16; return v.f;
}
__device__ __forceinline__ float tanh_fast(float x){
  float e = __expf(2.0f * x);
  return 1.0f - 2.0f / (e + 1.0f);
}

// W1[256][512] -> W1T hi/lo [512][256]; W2[512][256] -> W2T hi/lo [256][512].
__global__ void prep_weights(const float* __restrict__ W1, const float* __restrict__ W2,
                             unsigned short* __restrict__ W1h, unsigned short* __restrict__ W1l,
                             unsigned short* __restrict__ W2h, unsigned short* __restrict__ W2l){
  int idx = blockIdx.x * blockDim.x + threadIdx.x;
  if (idx >= DIN * DHID) return;
  {
    int k = idx / DHID, n = idx % DHID;
    float v = W1[idx];
    unsigned short h = f2bf(v);
    W1h[n * DIN + k] = h;
    W1l[n * DIN + k] = f2bf(v - bf2f(h));
  }
  {
    int k = idx / DIN, n = idx % DIN;
    float v = W2[idx];
    unsigned short h = f2bf(v);
    W2h[n * DHID + k] = h;
    W2l[n * DHID + k] = f2bf(v - bf2f(h));
  }
}

// Persistent RK4 integrator, round-6 structure (2 barriers/eval, full-width
// GEMM1) with the register budget pinned to the 256 tier:
// amdgpu_waves_per_eu(2,2) -> 2 waves/EU -> 256 unified regs/wave. Round 6
// proved the allocator caps at 128 otherwise and spills y/A/F (2.3 GB
// scratch writes + 11.7 GB reads/dispatch = the whole runtime). True peak
// pressure here is ~115 regs -> fits 256 with slack, zero spill.
__global__ __launch_bounds__(512) __attribute__((amdgpu_waves_per_eu(2, 2)))
void ode_all(const float* __restrict__ x, float* __restrict__ out,
             const unsigned short* __restrict__ W1h, const unsigned short* __restrict__ W1l,
             const unsigned short* __restrict__ W2h, const unsigned short* __restrict__ W2l,
             const float* __restrict__ b1, const float* __restrict__ b2)
{
  __shared__ unsigned short Ash[BM * APAD];    // 16.9 KB
  __shared__ unsigned short Hsh[BM * HPADW];   // 33.3 KB

  const int tid  = threadIdx.x;
  const int lane = tid & 63;
  const int wid  = tid >> 6;     // 0..7
  const int l15  = lane & 15;
  const int l4   = lane >> 4;    // 0..3
  const size_t r0 = (size_t)blockIdx.x * BM;

  // b2 columns this thread owns (used every A-stage/RK update -> registers);
  // b1 is read from global (L1-hot) once per eval in the tanh phase.
  float b2v[2];
  #pragma unroll
  for (int nt = 0; nt < 2; ++nt) b2v[nt] = b2[wid * 32 + nt * 16 + l15];

  // y/A/F in MFMA C-layout: row = rt*16 + l4*4 + r, col = wid*32 + nt*16 + l15
  float y[2][2][4], A[2][2][4];
  f32x4 F[2][2];
  #pragma unroll
  for (int rt = 0; rt < 2; ++rt)
    #pragma unroll
    for (int nt = 0; nt < 2; ++nt)
      #pragma unroll
      for (int r = 0; r < 4; ++r)
        y[rt][nt][r] = x[(r0 + rt * 16 + l4 * 4 + r) * DIN + wid * 32 + nt * 16 + l15];

  const float h = 1.0f / (float)NSTEPS;

  #pragma unroll 1
  for (int s = 0; s < NSTEPS; ++s){
    #pragma unroll 1
    for (int st = 0; st < 4; ++st){
      // ---- stage input X -> Ash (bf16). st0: y; st1/2: y+(h/2)k; st3: y+h*k ----
      const float cX = (st == 3) ? h : 0.5f * h;
      #pragma unroll
      for (int rt = 0; rt < 2; ++rt)
        #pragma unroll
        for (int nt = 0; nt < 2; ++nt)
          #pragma unroll
          for (int r = 0; r < 4; ++r){
            float xv = (st == 0) ? y[rt][nt][r]
                                 : fmaf(cX, F[rt][nt][r] + b2v[nt], y[rt][nt][r]);
            Ash[(rt * 16 + l4 * 4 + r) * APAD + wid * 32 + nt * 16 + l15] = f2bf(xv);
          }
      __syncthreads();                                   // BAR1: Ash ready

      // ---- GEMM1 full-width: U[32][wid*64 .. +64] = X * W1 (2-term W split) ----
      f32x4 acc1[2][4];
      #pragma unroll
      for (int rt = 0; rt < 2; ++rt)
        #pragma unroll
        for (int nt = 0; nt < 4; ++nt)
          acc1[rt][nt] = (f32x4){0.f, 0.f, 0.f, 0.f};

      #pragma unroll
      for (int ks = 0; ks < 8; ++ks){
        short8 af0 = *reinterpret_cast<const short8*>(&Ash[(     l15) * APAD + ks * 32 + l4 * 8]);
        short8 af1 = *reinterpret_cast<const short8*>(&Ash[(16 + l15) * APAD + ks * 32 + l4 * 8]);
        #pragma unroll
        for (int nt = 0; nt < 4; ++nt){
          int ncol = wid * 64 + nt * 16 + l15;
          int boff = ncol * DIN + ks * 32 + l4 * 8;
          short8 bh = *reinterpret_cast<const short8*>(W1h + boff);
          short8 bl = *reinterpret_cast<const short8*>(W1l + boff);
          acc1[0][nt] = __builtin_amdgcn_mfma_f32_16x16x32_bf16(af0, bh, acc1[0][nt], 0, 0, 0);
          acc1[0][nt] = __builtin_amdgcn_mfma_f32_16x16x32_bf16(af0, bl, acc1[0][nt], 0, 0, 0);
          acc1[1][nt] = __builtin_amdgcn_mfma_f32_16x16x32_bf16(af1, bh, acc1[1][nt], 0, 0, 0);
          acc1[1][nt] = __builtin_amdgcn_mfma_f32_16x16x32_bf16(af1, bl, acc1[1][nt], 0, 0, 0);
        }
      }

      // ---- bias + tanh -> Hsh (wave's 64 cols of all 512) ----
      #pragma unroll
      for (int nt = 0; nt < 4; ++nt){
        float bg = b1[wid * 64 + nt * 16 + l15];
        #pragma unroll
        for (int rt = 0; rt < 2; ++rt)
          #pragma unroll
          for (int r = 0; r < 4; ++r){
            float t = tanh_fast(acc1[rt][nt][r] + bg);
            Hsh[(rt * 16 + l4 * 4 + r) * HPADW + wid * 64 + nt * 16 + l15] = f2bf(t);
          }
      }
      __syncthreads();                                   // BAR2: Hsh ready, Ash free

      // ---- GEMM2: F[32][wid*32 .. +32] = H * W2 (2-term W split), K = 512 ----
      #pragma unroll
      for (int rt = 0; rt < 2; ++rt)
        #pragma unroll
        for (int nt = 0; nt < 2; ++nt)
          F[rt][nt] = (f32x4){0.f, 0.f, 0.f, 0.f};

      #pragma unroll
      for (int ks = 0; ks < 16; ++ks){
        short8 hf0 = *reinterpret_cast<const short8*>(&Hsh[(     l15) * HPADW + ks * 32 + l4 * 8]);
        short8 hf1 = *reinterpret_cast<const short8*>(&Hsh[(16 + l15) * HPADW + ks * 32 + l4 * 8]);
        #pragma unroll
        for (int nt = 0; nt < 2; ++nt){
          int ncol = wid * 32 + nt * 16 + l15;
          int boff = ncol * DHID + ks * 32 + l4 * 8;
          short8 bh = *reinterpret_cast<const short8*>(W2h + boff);
          short8 bl = *reinterpret_cast<const short8*>(W2l + boff);
          F[0][nt] = __builtin_amdgcn_mfma_f32_16x16x32_bf16(hf0, bh, F[0][nt], 0, 0, 0);
          F[0][nt] = __builtin_amdgcn_mfma_f32_16x16x32_bf16(hf0, bl, F[0][nt], 0, 0, 0);
          F[1][nt] = __builtin_amdgcn_mfma_f32_16x16x32_bf16(hf1, bh, F[1][nt], 0, 0, 0);
          F[1][nt] = __builtin_amdgcn_mfma_f32_16x16x32_bf16(hf1, bl, F[1][nt], 0, 0, 0);
        }
      }

      // ---- RK4 state update (k_st = F + b2) ----
      if (st == 0){
        #pragma unroll
        for (int rt = 0; rt < 2; ++rt)
          #pragma unroll
          for (int nt = 0; nt < 2; ++nt)
            #pragma unroll
            for (int r = 0; r < 4; ++r)
              A[rt][nt][r] = fmaf(h / 6.0f, F[rt][nt][r] + b2v[nt], y[rt][nt][r]);
      } else if (st == 1 || st == 2){
        #pragma unroll
        for (int rt = 0; rt < 2; ++rt)
          #pragma unroll
          for (int nt = 0; nt < 2; ++nt)
            #pragma unroll
            for (int r = 0; r < 4; ++r)
              A[rt][nt][r] = fmaf(h / 3.0f, F[rt][nt][r] + b2v[nt], A[rt][nt][r]);
      } else {
        #pragma unroll
        for (int rt = 0; rt < 2; ++rt)
          #pragma unroll
          for (int nt = 0; nt < 2; ++nt)
            #pragma unroll
            for (int r = 0; r < 4; ++r)
              y[rt][nt][r] = fmaf(h / 6.0f, F[rt][nt][r] + b2v[nt], A[rt][nt][r]);
      }
    }
  }

  // ---- write final state ----
  #pragma unroll
  for (int rt = 0; rt < 2; ++rt)
    #pragma unroll
    for (int nt = 0; nt < 2; ++nt)
      #pragma unroll
      for (int r = 0; r < 4; ++r)
        out[(r0 + rt * 16 + l4 * 4 + r) * DIN + wid * 32 + nt * 16 + l15] = y[rt][nt][r];
}

extern "C" void kernel_launch(void* const* d_in, const int* in_sizes, int n_in,
                              void* d_out, int out_size, void* d_ws, size_t ws_size,
                              hipStream_t stream)
{
  const float* x  = (const float*)d_in[0];
  const float* W1 = (const float*)d_in[1];
  const float* b1 = (const float*)d_in[2];
  const float* W2 = (const float*)d_in[3];
  const float* b2 = (const float*)d_in[4];
  float* out = (float*)d_out;

  unsigned short* W1h = (unsigned short*)d_ws;
  unsigned short* W1l = W1h + DIN * DHID;
  unsigned short* W2h = W1l + DIN * DHID;
  unsigned short* W2l = W2h + DIN * DHID;   // 1 MiB total

  prep_weights<<<512, 256, 0, stream>>>(W1, W2, W1h, W1l, W2h, W2l);
  ode_all<<<BATCH / BM, 512, 0, stream>>>(x, out, W1h, W1l, W2h, W2l, b1, b2);
}

// Round 8
// 3594.442 us; speedup vs baseline: 1.1576x; 1.1576x over previous
//
#include <hip/hip_runtime.h>

#define BATCH 65536
#define DIN   256
#define DHID  512
#define BM    32
#define APAD  264   // 256+8 shorts -> 132-word row stride; mod 32 = 4 -> ~2-way (free)
#define HPADW 520   // 512+8 shorts -> 260-word row stride; mod 32 = 4 -> ~2-way (free)
#define NSTEPS 4

typedef __attribute__((ext_vector_type(8))) short short8;
typedef __attribute__((ext_vector_type(4))) float f32x4;

__device__ __forceinline__ unsigned short f2bf(float f){
  union { float f; unsigned u; } v; v.f = f;
  unsigned u = v.u;
  unsigned r = (u + 0x7FFFu + ((u >> 16) & 1u)) >> 16;   // RN-even
  return (unsigned short)r;
}
__device__ __forceinline__ float bf2f(unsigned short h){
  union { float f; unsigned u; } v; v.u = ((unsigned)h) << 16; return v.f;
}
__device__ __forceinline__ float tanh_fast(float x){
  float e = __expf(2.0f * x);
  return 1.0f - 2.0f / (e + 1.0f);
}

// W1[256][512] -> W1T hi/lo [512][256]; W2[512][256] -> W2T hi/lo [256][512].
__global__ void prep_weights(const float* __restrict__ W1, const float* __restrict__ W2,
                             unsigned short* __restrict__ W1h, unsigned short* __restrict__ W1l,
                             unsigned short* __restrict__ W2h, unsigned short* __restrict__ W2l){
  int idx = blockIdx.x * blockDim.x + threadIdx.x;
  if (idx >= DIN * DHID) return;
  {
    int k = idx / DHID, n = idx % DHID;
    float v = W1[idx];
    unsigned short h = f2bf(v);
    W1h[n * DIN + k] = h;
    W1l[n * DIN + k] = f2bf(v - bf2f(h));
  }
  {
    int k = idx / DIN, n = idx % DIN;
    float v = W2[idx];
    unsigned short h = f2bf(v);
    W2h[n * DHID + k] = h;
    W2l[n * DHID + k] = f2bf(v - bf2f(h));
  }
}

// Persistent RK4 integrator. Combines r5's proven low register pressure
// (GEMM1 in 4 chunks, acc1 = 8 regs -> VGPR ~80, ZERO spill) with r6's
// 2-barrier structure (full-width Hsh buffer so chunk H-writes need no
// barriers: each wave writes only its own 16 H-columns per chunk and
// reads only them; cross-wave H consumption happens after BAR2).
// Rounds 2-4,6,7 lesson: hipcc caps 512-thread blocks at 128 VGPR no
// matter what attributes say, and spills GBs of scratch if pressure
// exceeds it — so pressure must genuinely fit.
__global__ __launch_bounds__(512, 2)
void ode_all(const float* __restrict__ x, float* __restrict__ out,
             const unsigned short* __restrict__ W1h, const unsigned short* __restrict__ W1l,
             const unsigned short* __restrict__ W2h, const unsigned short* __restrict__ W2l,
             const float* __restrict__ b1, const float* __restrict__ b2)
{
  __shared__ unsigned short Ash[BM * APAD];    // 16.9 KB
  __shared__ unsigned short Hsh[BM * HPADW];   // 33.3 KB (total 50 KB)

  const int tid  = threadIdx.x;
  const int lane = tid & 63;
  const int wid  = tid >> 6;     // 0..7
  const int l15  = lane & 15;
  const int l4   = lane >> 4;    // 0..3
  const size_t r0 = (size_t)blockIdx.x * BM;

  float b2v[2];
  #pragma unroll
  for (int nt = 0; nt < 2; ++nt) b2v[nt] = b2[wid * 32 + nt * 16 + l15];

  // y/A/F in MFMA C-layout: row = rt*16 + l4*4 + r, col = wid*32 + nt*16 + l15
  float y[2][2][4], A[2][2][4];
  f32x4 F[2][2];
  #pragma unroll
  for (int rt = 0; rt < 2; ++rt)
    #pragma unroll
    for (int nt = 0; nt < 2; ++nt)
      #pragma unroll
      for (int r = 0; r < 4; ++r)
        y[rt][nt][r] = x[(r0 + rt * 16 + l4 * 4 + r) * DIN + wid * 32 + nt * 16 + l15];

  const float h = 1.0f / (float)NSTEPS;

  #pragma unroll 1
  for (int s = 0; s < NSTEPS; ++s){
    #pragma unroll 1
    for (int st = 0; st < 4; ++st){
      // ---- stage input X -> Ash (bf16). st0: y; st1/2: y+(h/2)k; st3: y+h*k ----
      const float cX = (st == 3) ? h : 0.5f * h;
      #pragma unroll
      for (int rt = 0; rt < 2; ++rt)
        #pragma unroll
        for (int nt = 0; nt < 2; ++nt)
          #pragma unroll
          for (int r = 0; r < 4; ++r){
            float xv = (st == 0) ? y[rt][nt][r]
                                 : fmaf(cX, F[rt][nt][r] + b2v[nt], y[rt][nt][r]);
            Ash[(rt * 16 + l4 * 4 + r) * APAD + wid * 32 + nt * 16 + l15] = f2bf(xv);
          }
      __syncthreads();                                   // BAR1: Ash ready

      // ---- GEMM1 in 4 chunks (acc1 = 8 regs), H-writes barrier-free ----
      #pragma unroll 1
      for (int ch = 0; ch < 4; ++ch){
        f32x4 acc1[2];
        acc1[0] = (f32x4){0.f, 0.f, 0.f, 0.f};
        acc1[1] = (f32x4){0.f, 0.f, 0.f, 0.f};

        #pragma unroll
        for (int ks = 0; ks < 8; ++ks){
          short8 af0 = *reinterpret_cast<const short8*>(&Ash[(     l15) * APAD + ks * 32 + l4 * 8]);
          short8 af1 = *reinterpret_cast<const short8*>(&Ash[(16 + l15) * APAD + ks * 32 + l4 * 8]);
          int ncol = ch * 128 + wid * 16 + l15;
          int boff = ncol * DIN + ks * 32 + l4 * 8;
          short8 bh = *reinterpret_cast<const short8*>(W1h + boff);
          short8 bl = *reinterpret_cast<const short8*>(W1l + boff);
          acc1[0] = __builtin_amdgcn_mfma_f32_16x16x32_bf16(af0, bh, acc1[0], 0, 0, 0);
          acc1[0] = __builtin_amdgcn_mfma_f32_16x16x32_bf16(af0, bl, acc1[0], 0, 0, 0);
          acc1[1] = __builtin_amdgcn_mfma_f32_16x16x32_bf16(af1, bh, acc1[1], 0, 0, 0);
          acc1[1] = __builtin_amdgcn_mfma_f32_16x16x32_bf16(af1, bl, acc1[1], 0, 0, 0);
        }

        // bias + tanh -> wave's 16 H-columns of this chunk (no barrier:
        // only this wave reads/writes these columns until after BAR2)
        {
          float bg = b1[ch * 128 + wid * 16 + l15];
          #pragma unroll
          for (int rt = 0; rt < 2; ++rt)
            #pragma unroll
            for (int r = 0; r < 4; ++r){
              float t = tanh_fast(acc1[rt][r] + bg);
              Hsh[(rt * 16 + l4 * 4 + r) * HPADW + ch * 128 + wid * 16 + l15] = f2bf(t);
            }
        }
      }
      __syncthreads();                                   // BAR2: Hsh ready, Ash free

      // ---- GEMM2: F[32][wid*32 .. +32] = H * W2 (2-term W split), K = 512 ----
      #pragma unroll
      for (int rt = 0; rt < 2; ++rt)
        #pragma unroll
        for (int nt = 0; nt < 2; ++nt)
          F[rt][nt] = (f32x4){0.f, 0.f, 0.f, 0.f};

      #pragma unroll
      for (int ks = 0; ks < 16; ++ks){
        short8 hf0 = *reinterpret_cast<const short8*>(&Hsh[(     l15) * HPADW + ks * 32 + l4 * 8]);
        short8 hf1 = *reinterpret_cast<const short8*>(&Hsh[(16 + l15) * HPADW + ks * 32 + l4 * 8]);
        #pragma unroll
        for (int nt = 0; nt < 2; ++nt){
          int ncol = wid * 32 + nt * 16 + l15;
          int boff = ncol * DHID + ks * 32 + l4 * 8;
          short8 bh = *reinterpret_cast<const short8*>(W2h + boff);
          short8 bl = *reinterpret_cast<const short8*>(W2l + boff);
          F[0][nt] = __builtin_amdgcn_mfma_f32_16x16x32_bf16(hf0, bh, F[0][nt], 0, 0, 0);
          F[0][nt] = __builtin_amdgcn_mfma_f32_16x16x32_bf16(hf0, bl, F[0][nt], 0, 0, 0);
          F[1][nt] = __builtin_amdgcn_mfma_f32_16x16x32_bf16(hf1, bh, F[1][nt], 0, 0, 0);
          F[1][nt] = __builtin_amdgcn_mfma_f32_16x16x32_bf16(hf1, bl, F[1][nt], 0, 0, 0);
        }
      }

      // ---- RK4 state update (k_st = F + b2) ----
      if (st == 0){
        #pragma unroll
        for (int rt = 0; rt < 2; ++rt)
          #pragma unroll
          for (int nt = 0; nt < 2; ++nt)
            #pragma unroll
            for (int r = 0; r < 4; ++r)
              A[rt][nt][r] = fmaf(h / 6.0f, F[rt][nt][r] + b2v[nt], y[rt][nt][r]);
      } else if (st == 1 || st == 2){
        #pragma unroll
        for (int rt = 0; rt < 2; ++rt)
          #pragma unroll
          for (int nt = 0; nt < 2; ++nt)
            #pragma unroll
            for (int r = 0; r < 4; ++r)
              A[rt][nt][r] = fmaf(h / 3.0f, F[rt][nt][r] + b2v[nt], A[rt][nt][r]);
      } else {
        #pragma unroll
        for (int rt = 0; rt < 2; ++rt)
          #pragma unroll
          for (int nt = 0; nt < 2; ++nt)
            #pragma unroll
            for (int r = 0; r < 4; ++r)
              y[rt][nt][r] = fmaf(h / 6.0f, F[rt][nt][r] + b2v[nt], A[rt][nt][r]);
      }
    }
  }

  // ---- write final state ----
  #pragma unroll
  for (int rt = 0; rt < 2; ++rt)
    #pragma unroll
    for (int nt = 0; nt < 2; ++nt)
      #pragma unroll
      for (int r = 0; r < 4; ++r)
        out[(r0 + rt * 16 + l4 * 4 + r) * DIN + wid * 32 + nt * 16 + l15] = y[rt][nt][r];
}

extern "C" void kernel_launch(void* const* d_in, const int* in_sizes, int n_in,
                              void* d_out, int out_size, void* d_ws, size_t ws_size,
                              hipStream_t stream)
{
  const float* x  = (const float*)d_in[0];
  const float* W1 = (const float*)d_in[1];
  const float* b1 = (const float*)d_in[2];
  const float* W2 = (const float*)d_in[3];
  const float* b2 = (const float*)d_in[4];
  float* out = (float*)d_out;

  unsigned short* W1h = (unsigned short*)d_ws;
  unsigned short* W1l = W1h + DIN * DHID;
  unsigned short* W2h = W1l + DIN * DHID;
  unsigned short* W2l = W2h + DIN * DHID;   // 1 MiB total

  prep_weights<<<512, 256, 0, stream>>>(W1, W2, W1h, W1l, W2h, W2l);
  ode_all<<<BATCH / BM, 512, 0, stream>>>(x, out, W1h, W1l, W2h, W2l, b1, b2);
}

// Round 9
// 1415.145 us; speedup vs baseline: 2.9403x; 2.5400x over previous
//
#include <hip/hip_runtime.h>

#define BATCH 65536
#define DIN   256
#define DHID  512
#define BM    32
#define APAD  264   // 256+8 shorts -> 132-word row stride; mod 32 = 4 -> ~2-way (free)
#define HPADW 520   // 512+8 shorts -> 260-word row stride; mod 32 = 4 -> ~2-way (free)
#define NSTEPS 4

typedef __attribute__((ext_vector_type(8))) short short8;
typedef __attribute__((ext_vector_type(4))) float f32x4;

__device__ __forceinline__ unsigned short f2bf(float f){
  union { float f; unsigned u; } v; v.f = f;
  unsigned u = v.u;
  unsigned r = (u + 0x7FFFu + ((u >> 16) & 1u)) >> 16;   // RN-even
  return (unsigned short)r;
}
__device__ __forceinline__ float tanh_fast(float x){
  float e = __expf(2.0f * x);
  return 1.0f - 2.0f / (e + 1.0f);
}

// Transpose weights once: W1[256][512] -> W1T[512][256] bf16;
// W2[512][256] -> W2T[256][512] bf16. (1-term: absmax was 0.03125
// identically with 3-term, 2-term, and now — error is dominated by the
// bf16 A/H staging, not weight precision.)
__global__ void prep_weights(const float* __restrict__ W1, const float* __restrict__ W2,
                             unsigned short* __restrict__ W1t, unsigned short* __restrict__ W2t){
  int idx = blockIdx.x * blockDim.x + threadIdx.x;
  if (idx >= DIN * DHID) return;
  {
    int k = idx / DHID, n = idx % DHID;
    W1t[n * DIN + k] = f2bf(W1[idx]);
  }
  {
    int k = idx / DIN, n = idx % DIN;
    W2t[n * DHID + k] = f2bf(W2[idx]);
  }
}

// Persistent RK4 integrator, r8 structure (2 barriers/eval, chunked GEMM1
// with barrier-free H-writes) + 1-term bf16 weights. The 1-term change
// halves MFMA work, weight traffic, AND in-flight fragment registers —
// peak pressure ~95-110 now genuinely fits the 128-VGPR cap that hipcc
// enforces for 512-thread blocks (rounds 2-8: any overflow = GBs of
// scratch spill traffic at ~3 TB/s, the whole runtime).
__global__ __launch_bounds__(512, 2)
void ode_all(const float* __restrict__ x, float* __restrict__ out,
             const unsigned short* __restrict__ W1t, const unsigned short* __restrict__ W2t,
             const float* __restrict__ b1, const float* __restrict__ b2)
{
  __shared__ unsigned short Ash[BM * APAD];    // 16.9 KB
  __shared__ unsigned short Hsh[BM * HPADW];   // 33.3 KB (total 50 KB)

  const int tid  = threadIdx.x;
  const int lane = tid & 63;
  const int wid  = tid >> 6;     // 0..7
  const int l15  = lane & 15;
  const int l4   = lane >> 4;    // 0..3
  const size_t r0 = (size_t)blockIdx.x * BM;

  float b2v[2];
  #pragma unroll
  for (int nt = 0; nt < 2; ++nt) b2v[nt] = b2[wid * 32 + nt * 16 + l15];

  // y/A/F in MFMA C-layout: row = rt*16 + l4*4 + r, col = wid*32 + nt*16 + l15
  float y[2][2][4], A[2][2][4];
  f32x4 F[2][2];
  #pragma unroll
  for (int rt = 0; rt < 2; ++rt)
    #pragma unroll
    for (int nt = 0; nt < 2; ++nt)
      #pragma unroll
      for (int r = 0; r < 4; ++r)
        y[rt][nt][r] = x[(r0 + rt * 16 + l4 * 4 + r) * DIN + wid * 32 + nt * 16 + l15];

  const float h = 1.0f / (float)NSTEPS;

  #pragma unroll 1
  for (int s = 0; s < NSTEPS; ++s){
    #pragma unroll 1
    for (int st = 0; st < 4; ++st){
      // ---- stage input X -> Ash (bf16). st0: y; st1/2: y+(h/2)k; st3: y+h*k ----
      const float cX = (st == 3) ? h : 0.5f * h;
      #pragma unroll
      for (int rt = 0; rt < 2; ++rt)
        #pragma unroll
        for (int nt = 0; nt < 2; ++nt)
          #pragma unroll
          for (int r = 0; r < 4; ++r){
            float xv = (st == 0) ? y[rt][nt][r]
                                 : fmaf(cX, F[rt][nt][r] + b2v[nt], y[rt][nt][r]);
            Ash[(rt * 16 + l4 * 4 + r) * APAD + wid * 32 + nt * 16 + l15] = f2bf(xv);
          }
      __syncthreads();                                   // BAR1: Ash ready

      // ---- GEMM1 in 4 chunks (acc1 = 8 regs), H-writes barrier-free ----
      #pragma unroll 1
      for (int ch = 0; ch < 4; ++ch){
        f32x4 acc1[2];
        acc1[0] = (f32x4){0.f, 0.f, 0.f, 0.f};
        acc1[1] = (f32x4){0.f, 0.f, 0.f, 0.f};

        #pragma unroll
        for (int ks = 0; ks < 8; ++ks){
          short8 af0 = *reinterpret_cast<const short8*>(&Ash[(     l15) * APAD + ks * 32 + l4 * 8]);
          short8 af1 = *reinterpret_cast<const short8*>(&Ash[(16 + l15) * APAD + ks * 32 + l4 * 8]);
          int ncol = ch * 128 + wid * 16 + l15;
          short8 bh = *reinterpret_cast<const short8*>(W1t + ncol * DIN + ks * 32 + l4 * 8);
          acc1[0] = __builtin_amdgcn_mfma_f32_16x16x32_bf16(af0, bh, acc1[0], 0, 0, 0);
          acc1[1] = __builtin_amdgcn_mfma_f32_16x16x32_bf16(af1, bh, acc1[1], 0, 0, 0);
        }

        // bias + tanh -> wave's 16 H-columns of this chunk (no barrier:
        // only this wave touches these columns until after BAR2)
        {
          float bg = b1[ch * 128 + wid * 16 + l15];
          #pragma unroll
          for (int rt = 0; rt < 2; ++rt)
            #pragma unroll
            for (int r = 0; r < 4; ++r){
              float t = tanh_fast(acc1[rt][r] + bg);
              Hsh[(rt * 16 + l4 * 4 + r) * HPADW + ch * 128 + wid * 16 + l15] = f2bf(t);
            }
        }
      }
      __syncthreads();                                   // BAR2: Hsh ready, Ash free

      // ---- GEMM2: F[32][wid*32 .. +32] = H * W2 (1-term), K = 512 ----
      #pragma unroll
      for (int rt = 0; rt < 2; ++rt)
        #pragma unroll
        for (int nt = 0; nt < 2; ++nt)
          F[rt][nt] = (f32x4){0.f, 0.f, 0.f, 0.f};

      #pragma unroll
      for (int ks = 0; ks < 16; ++ks){
        short8 hf0 = *reinterpret_cast<const short8*>(&Hsh[(     l15) * HPADW + ks * 32 + l4 * 8]);
        short8 hf1 = *reinterpret_cast<const short8*>(&Hsh[(16 + l15) * HPADW + ks * 32 + l4 * 8]);
        #pragma unroll
        for (int nt = 0; nt < 2; ++nt){
          int ncol = wid * 32 + nt * 16 + l15;
          short8 bh = *reinterpret_cast<const short8*>(W2t + ncol * DHID + ks * 32 + l4 * 8);
          F[0][nt] = __builtin_amdgcn_mfma_f32_16x16x32_bf16(hf0, bh, F[0][nt], 0, 0, 0);
          F[1][nt] = __builtin_amdgcn_mfma_f32_16x16x32_bf16(hf1, bh, F[1][nt], 0, 0, 0);
        }
      }

      // ---- RK4 state update (k_st = F + b2) ----
      if (st == 0){
        #pragma unroll
        for (int rt = 0; rt < 2; ++rt)
          #pragma unroll
          for (int nt = 0; nt < 2; ++nt)
            #pragma unroll
            for (int r = 0; r < 4; ++r)
              A[rt][nt][r] = fmaf(h / 6.0f, F[rt][nt][r] + b2v[nt], y[rt][nt][r]);
      } else if (st == 1 || st == 2){
        #pragma unroll
        for (int rt = 0; rt < 2; ++rt)
          #pragma unroll
          for (int nt = 0; nt < 2; ++nt)
            #pragma unroll
            for (int r = 0; r < 4; ++r)
              A[rt][nt][r] = fmaf(h / 3.0f, F[rt][nt][r] + b2v[nt], A[rt][nt][r]);
      } else {
        #pragma unroll
        for (int rt = 0; rt < 2; ++rt)
          #pragma unroll
          for (int nt = 0; nt < 2; ++nt)
            #pragma unroll
            for (int r = 0; r < 4; ++r)
              y[rt][nt][r] = fmaf(h / 6.0f, F[rt][nt][r] + b2v[nt], A[rt][nt][r]);
      }
    }
  }

  // ---- write final state ----
  #pragma unroll
  for (int rt = 0; rt < 2; ++rt)
    #pragma unroll
    for (int nt = 0; nt < 2; ++nt)
      #pragma unroll
      for (int r = 0; r < 4; ++r)
        out[(r0 + rt * 16 + l4 * 4 + r) * DIN + wid * 32 + nt * 16 + l15] = y[rt][nt][r];
}

extern "C" void kernel_launch(void* const* d_in, const int* in_sizes, int n_in,
                              void* d_out, int out_size, void* d_ws, size_t ws_size,
                              hipStream_t stream)
{
  const float* x  = (const float*)d_in[0];
  const float* W1 = (const float*)d_in[1];
  const float* b1 = (const float*)d_in[2];
  const float* W2 = (const float*)d_in[3];
  const float* b2 = (const float*)d_in[4];
  float* out = (float*)d_out;

  unsigned short* W1t = (unsigned short*)d_ws;
  unsigned short* W2t = W1t + DIN * DHID;   // 512 KiB total

  prep_weights<<<512, 256, 0, stream>>>(W1, W2, W1t, W2t);
  ode_all<<<BATCH / BM, 512, 0, stream>>>(x, out, W1t, W2t, b1, b2);
}

// Round 10
// 960.217 us; speedup vs baseline: 4.3333x; 1.4738x over previous
//
#include <hip/hip_runtime.h>

#define BATCH 65536
#define DIN   256
#define DHID  512
#define BM    32
#define APAD  264   // 256+8 shorts -> 132-dword row stride; mod 32 = 4 -> balanced banks
#define HPADW 520   // 512+8 shorts -> 260-dword row stride; mod 32 = 4 -> balanced banks
#define NSTEPS 4

typedef __attribute__((ext_vector_type(8))) short short8;
typedef __attribute__((ext_vector_type(4))) float f32x4;

__device__ __forceinline__ unsigned short f2bf(float f){
  union { float f; unsigned u; } v; v.f = f;
  unsigned u = v.u;
  unsigned r = (u + 0x7FFFu + ((u >> 16) & 1u)) >> 16;   // RN-even
  return (unsigned short)r;
}
__device__ __forceinline__ float tanh_fast(float x){
  float e = __expf(2.0f * x);
  return 1.0f - 2.0f / (e + 1.0f);
}

// Pack weights in per-wave MFMA fragment order so kernel weight loads are
// base + lane*16B (fully coalesced 1KB/instruction, linear streaming).
// r9 lesson: ncol*DIN addressing made every weight load a 16-line gather
// (512B row stride across l15 lanes) -> TA/L1 transaction-bound.
// W1p[((ch*8+wid)*8+ks)*512 + lane*8 + j] = W1[k][n],
//   n = ch*128+wid*16+(lane&15), k = ks*32+(lane>>4)*8+j
// W2p[((wid*2+nt)*16+ks)*512 + lane*8 + j] = W2[k][n],
//   n = wid*32+nt*16+(lane&15), k = ks*32+(lane>>4)*8+j
__global__ void prep_pack(const float* __restrict__ W1, const float* __restrict__ W2,
                          unsigned short* __restrict__ W1p, unsigned short* __restrict__ W2p){
  int idx = blockIdx.x * blockDim.x + threadIdx.x;
  if (idx >= DIN * DHID) return;
  {
    int j = idx & 7, lane = (idx >> 3) & 63, ks = (idx >> 9) & 7,
        wid = (idx >> 12) & 7, ch = idx >> 15;
    int n = ch * 128 + wid * 16 + (lane & 15);
    int k = ks * 32 + (lane >> 4) * 8 + j;
    W1p[idx] = f2bf(W1[k * DHID + n]);
  }
  {
    int j = idx & 7, lane = (idx >> 3) & 63, ks = (idx >> 9) & 15,
        nt = (idx >> 13) & 1, wid = idx >> 14;
    int n = wid * 32 + nt * 16 + (lane & 15);
    int k = ks * 32 + (lane >> 4) * 8 + j;
    W2p[idx] = f2bf(W2[k * DIN + n]);
  }
}

// Persistent RK4 integrator (r9 structure: 2 barriers/eval, chunked GEMM1
// with barrier-free H-writes, 1-term bf16 weights, pressure fits the
// 128-VGPR cap) + fragment-packed coalesced weight loads.
__global__ __launch_bounds__(512, 2)
void ode_all(const float* __restrict__ x, float* __restrict__ out,
             const unsigned short* __restrict__ W1p, const unsigned short* __restrict__ W2p,
             const float* __restrict__ b1, const float* __restrict__ b2)
{
  __shared__ unsigned short Ash[BM * APAD];    // 16.9 KB
  __shared__ unsigned short Hsh[BM * HPADW];   // 33.3 KB (total 50 KB)

  const int tid  = threadIdx.x;
  const int lane = tid & 63;
  const int wid  = tid >> 6;     // 0..7
  const int l15  = lane & 15;
  const int l4   = lane >> 4;    // 0..3
  const size_t r0 = (size_t)blockIdx.x * BM;

  float b2v[2];
  #pragma unroll
  for (int nt = 0; nt < 2; ++nt) b2v[nt] = b2[wid * 32 + nt * 16 + l15];

  // y/A/F in MFMA C-layout: row = rt*16 + l4*4 + r, col = wid*32 + nt*16 + l15
  float y[2][2][4], A[2][2][4];
  f32x4 F[2][2];
  #pragma unroll
  for (int rt = 0; rt < 2; ++rt)
    #pragma unroll
    for (int nt = 0; nt < 2; ++nt)
      #pragma unroll
      for (int r = 0; r < 4; ++r)
        y[rt][nt][r] = x[(r0 + rt * 16 + l4 * 4 + r) * DIN + wid * 32 + nt * 16 + l15];

  const float h = 1.0f / (float)NSTEPS;

  // linear fragment-stream bases (shorts)
  const unsigned short* w1w = W1p + (size_t)wid * (8 * 512) + (lane << 3);       // + ch*8*8*512/8?  see below
  const unsigned short* w2b0 = W2p + ((size_t)(wid * 2 + 0) * 16) * 512 + (lane << 3);
  const unsigned short* w2b1 = W2p + ((size_t)(wid * 2 + 1) * 16) * 512 + (lane << 3);

  #pragma unroll 1
  for (int s = 0; s < NSTEPS; ++s){
    #pragma unroll 1
    for (int st = 0; st < 4; ++st){
      // ---- stage input X -> Ash (bf16). st0: y; st1/2: y+(h/2)k; st3: y+h*k ----
      const float cX = (st == 3) ? h : 0.5f * h;
      #pragma unroll
      for (int rt = 0; rt < 2; ++rt)
        #pragma unroll
        for (int nt = 0; nt < 2; ++nt)
          #pragma unroll
          for (int r = 0; r < 4; ++r){
            float xv = (st == 0) ? y[rt][nt][r]
                                 : fmaf(cX, F[rt][nt][r] + b2v[nt], y[rt][nt][r]);
            Ash[(rt * 16 + l4 * 4 + r) * APAD + wid * 32 + nt * 16 + l15] = f2bf(xv);
          }
      __syncthreads();                                   // BAR1: Ash ready

      // ---- GEMM1 in 4 chunks (acc1 = 8 regs), H-writes barrier-free ----
      #pragma unroll 1
      for (int ch = 0; ch < 4; ++ch){
        f32x4 acc1[2];
        acc1[0] = (f32x4){0.f, 0.f, 0.f, 0.f};
        acc1[1] = (f32x4){0.f, 0.f, 0.f, 0.f};

        // wave's packed W1 stream for this chunk: 8 contiguous 1KB blocks
        const unsigned short* w1c = W1p + ((size_t)(ch * 8 + wid) * 8) * 512 + (lane << 3);

        #pragma unroll
        for (int ks = 0; ks < 8; ++ks){
          short8 af0 = *reinterpret_cast<const short8*>(&Ash[(     l15) * APAD + ks * 32 + l4 * 8]);
          short8 af1 = *reinterpret_cast<const short8*>(&Ash[(16 + l15) * APAD + ks * 32 + l4 * 8]);
          short8 bh  = *reinterpret_cast<const short8*>(w1c + (size_t)ks * 512);
          acc1[0] = __builtin_amdgcn_mfma_f32_16x16x32_bf16(af0, bh, acc1[0], 0, 0, 0);
          acc1[1] = __builtin_amdgcn_mfma_f32_16x16x32_bf16(af1, bh, acc1[1], 0, 0, 0);
        }

        // bias + tanh -> wave's 16 H-columns of this chunk (no barrier:
        // only this wave touches these columns until after BAR2)
        {
          float bg = b1[ch * 128 + wid * 16 + l15];
          #pragma unroll
          for (int rt = 0; rt < 2; ++rt)
            #pragma unroll
            for (int r = 0; r < 4; ++r){
              float t = tanh_fast(acc1[rt][r] + bg);
              Hsh[(rt * 16 + l4 * 4 + r) * HPADW + ch * 128 + wid * 16 + l15] = f2bf(t);
            }
        }
      }
      __syncthreads();                                   // BAR2: Hsh ready, Ash free

      // ---- GEMM2: F[32][wid*32 .. +32] = H * W2 (1-term), K = 512 ----
      #pragma unroll
      for (int rt = 0; rt < 2; ++rt)
        #pragma unroll
        for (int nt = 0; nt < 2; ++nt)
          F[rt][nt] = (f32x4){0.f, 0.f, 0.f, 0.f};

      #pragma unroll
      for (int ks = 0; ks < 16; ++ks){
        short8 hf0 = *reinterpret_cast<const short8*>(&Hsh[(     l15) * HPADW + ks * 32 + l4 * 8]);
        short8 hf1 = *reinterpret_cast<const short8*>(&Hsh[(16 + l15) * HPADW + ks * 32 + l4 * 8]);
        short8 b0  = *reinterpret_cast<const short8*>(w2b0 + (size_t)ks * 512);
        short8 b1f = *reinterpret_cast<const short8*>(w2b1 + (size_t)ks * 512);
        F[0][0] = __builtin_amdgcn_mfma_f32_16x16x32_bf16(hf0, b0,  F[0][0], 0, 0, 0);
        F[1][0] = __builtin_amdgcn_mfma_f32_16x16x32_bf16(hf1, b0,  F[1][0], 0, 0, 0);
        F[0][1] = __builtin_amdgcn_mfma_f32_16x16x32_bf16(hf0, b1f, F[0][1], 0, 0, 0);
        F[1][1] = __builtin_amdgcn_mfma_f32_16x16x32_bf16(hf1, b1f, F[1][1], 0, 0, 0);
      }

      // ---- RK4 state update (k_st = F + b2) ----
      if (st == 0){
        #pragma unroll
        for (int rt = 0; rt < 2; ++rt)
          #pragma unroll
          for (int nt = 0; nt < 2; ++nt)
            #pragma unroll
            for (int r = 0; r < 4; ++r)
              A[rt][nt][r] = fmaf(h / 6.0f, F[rt][nt][r] + b2v[nt], y[rt][nt][r]);
      } else if (st == 1 || st == 2){
        #pragma unroll
        for (int rt = 0; rt < 2; ++rt)
          #pragma unroll
          for (int nt = 0; nt < 2; ++nt)
            #pragma unroll
            for (int r = 0; r < 4; ++r)
              A[rt][nt][r] = fmaf(h / 3.0f, F[rt][nt][r] + b2v[nt], A[rt][nt][r]);
      } else {
        #pragma unroll
        for (int rt = 0; rt < 2; ++rt)
          #pragma unroll
          for (int nt = 0; nt < 2; ++nt)
            #pragma unroll
            for (int r = 0; r < 4; ++r)
              y[rt][nt][r] = fmaf(h / 6.0f, F[rt][nt][r] + b2v[nt], A[rt][nt][r]);
      }
    }
  }

  // ---- write final state ----
  #pragma unroll
  for (int rt = 0; rt < 2; ++rt)
    #pragma unroll
    for (int nt = 0; nt < 2; ++nt)
      #pragma unroll
      for (int r = 0; r < 4; ++r)
        out[(r0 + rt * 16 + l4 * 4 + r) * DIN + wid * 32 + nt * 16 + l15] = y[rt][nt][r];
}

extern "C" void kernel_launch(void* const* d_in, const int* in_sizes, int n_in,
                              void* d_out, int out_size, void* d_ws, size_t ws_size,
                              hipStream_t stream)
{
  const float* x  = (const float*)d_in[0];
  const float* W1 = (const float*)d_in[1];
  const float* b1 = (const float*)d_in[2];
  const float* W2 = (const float*)d_in[3];
  const float* b2 = (const float*)d_in[4];
  float* out = (float*)d_out;

  unsigned short* W1p = (unsigned short*)d_ws;
  unsigned short* W2p = W1p + DIN * DHID;   // 512 KiB total

  prep_pack<<<512, 256, 0, stream>>>(W1, W2, W1p, W2p);
  ode_all<<<BATCH / BM, 512, 0, stream>>>(x, out, W1p, W2p, b1, b2);
}